// Round 16
// baseline (56.131 us; speedup 1.0000x reference)
//
#include <hip/hip_runtime.h>
#include <math.h>

#define NTOK 16384
#define D_   2048
#define E_   64
#define TPB  64            // tokens per block
#define NKC  (D_/32)       // 64 k32-steps
#define NCH  32            // chunks of 2 kc

typedef _Float16 f16x8 __attribute__((ext_vector_type(8)));
typedef float    f32x4 __attribute__((ext_vector_type(4)));

#define LSCALE      256.0f          // pre-scale x and W before f16 split (denorm guard)
#define LSCALE2_INV (1.0f/65536.0f) // exact pow2 un-scale of acc

// LDS: 4 chunk-buffers of 32768 B at (c&3)*32768 (total 128 KB).
// Buffer: x region 16 KB = 2 kc-pages x [64 rows][8 slots x 16B] (slot XOR-
// swizzled by row&7; src pre-swizzled, LDS linear, read swizzled - r7-proven);
// B region at +16384: [2 pages][4 nt][hi 1KB | lo 1KB].
// Pipeline r7-proven: STAGE(c+3) overwrites buf[(c-1)&3], consumed in iter
// c-1 with a barrier since -> race-free. Epilogue logits [64][65]+res alias
// buf0 (last read chunk 28).
#define SMEM_FLOATS 32768          // 128 KB

// ---- Kernel 1: W (E x D fp32) -> fragment-ordered f16 hi/lo, scaled x256 ----
// Fragment order: element j of lane l for (n-tile nt, k32-step kc) is
//   W[e = nt*16 + (l&15)][k = kc*32 + (l>>4)*4 + (j&3) + (j>=4 ? 16 : 0)]
// Same k-map as the A operand -> any deviation from HW k-order cancels.
__global__ __launch_bounds__(256)
void prep_w(const float* __restrict__ W,
            _Float16* __restrict__ wh, _Float16* __restrict__ wl)
{
    const int idx = blockIdx.x * 256 + threadIdx.x;   // 0..16383
    const int l  = idx & 63;
    const int kc = (idx >> 6) & 63;
    const int nt = idx >> 12;                          // 0..3
    const int e  = nt * 16 + (l & 15);
    const int g  = l >> 4;
    const float* src = W + (size_t)e * D_ + kc * 32 + g * 4;
    const float4 f0 = *reinterpret_cast<const float4*>(src);
    const float4 f1 = *reinterpret_cast<const float4*>(src + 16);
    const float v[8] = {f0.x, f0.y, f0.z, f0.w, f1.x, f1.y, f1.z, f1.w};
    f16x8 h, lo;
#pragma unroll
    for (int j = 0; j < 8; ++j) {
        const float vs = v[j] * LSCALE;
        const _Float16 hj = (_Float16)vs;
        h[j]  = hj;
        lo[j] = (_Float16)(vs - (float)hj);
    }
    *reinterpret_cast<f16x8*>(wh + (size_t)idx * 8) = h;
    *reinterpret_cast<f16x8*>(wl + (size_t)idx * 8) = lo;
}

__device__ __forceinline__ void stage16(const void* g, void* l) {
    __builtin_amdgcn_global_load_lds(
        (const __attribute__((address_space(1))) void*)g,
        (__attribute__((address_space(3))) void*)l, 16, 0, 0);
}

// ---- Kernel 2: MFMA router -- LDS-resident pipeline, B read once/block ----
// 256 blocks x 256 threads (4 waves, 64 tokens, 1 block/CU).
// Wave w = tokens w*16..w*16+15, ALL 64 experts (token-split: x cvt once,
// B shared via LDS -> B traffic 128 MB total, 4x less than r12's reg-stream;
// L2 line-requests ~10.4M -> ~4M, the quantity all r5-r15 plateaus track).
// The prefetch pipeline lives in LDS via global_load_lds + counted vmcnt --
// a structure hipcc CANNOT collapse (r12-r15: every VGPR ring got collapsed,
// VGPR 52..132 vs ~190 needed).
// Per chunk c (2 kc): vmcnt(16) [chunk c landed; c+1,c+2 in flight] ->
// barrier -> STAGE(c+3) [8x16B/wave] -> COMPUTE (2 kc x {10 ds_read, cvt,
// 12 MFMA}). Tail vmcnt 16/8/0.
// Per-(token,expert) chain (hh,lh,hl; kc ascending; same fragment maps) is
// bitwise-identical to rounds 5-15 (absmax 1.0; do NOT reorder).
__global__ __launch_bounds__(256, 1)
void router_mfma(const float* __restrict__ x,
                 const _Float16* __restrict__ wh,
                 const _Float16* __restrict__ wl,
                 const float* __restrict__ bias,
                 float* __restrict__ out)
{
    __shared__ float smem[SMEM_FLOATS];
    char* sb = (char*)smem;

    const int tid = threadIdx.x;
    const int l   = tid & 63;
    const int w   = __builtin_amdgcn_readfirstlane(tid >> 6);  // 0..3
    const int T0  = blockIdx.x * TPB;
    const int g   = l >> 4;

    f32x4 acc0 = {0.f,0.f,0.f,0.f}, acc1 = {0.f,0.f,0.f,0.f};
    f32x4 acc2 = {0.f,0.f,0.f,0.f}, acc3 = {0.f,0.f,0.f,0.f};

    // --- staging sources (wave w stages its own 16 x-rows + nt=w's B) ---
    // x instr i in {0,1}: rows r = w*16 + 8i + (l>>3); linear slot l&7 holds
    // source slot (l&7)^(r&7); r&7 = (l>>3)&7.
    const int rlo   = l >> 3;                         // 0..7
    const int sslot = (l & 7) ^ (rlo & 7);
    const float* xs0 = x + (size_t)(T0 + w*16 + 0 + rlo) * D_ + sslot * 4;
    const float* xs1 = x + (size_t)(T0 + w*16 + 8 + rlo) * D_ + sslot * 4;
    const _Float16* bhs = wh + (size_t)w * NKC * 512 / 8 * 8;  // w*NKC*512 halves
    const _Float16* bls = wl + (size_t)w * NKC * 512;
    const _Float16* bhs_ = wh + (size_t)w * NKC * 512;

    auto STAGE = [&](int c) {               // 8 x 16B global_load_lds
        char* bb = sb + (size_t)(c & 3) * 32768;
        const int kc0 = c * 2;
#pragma unroll
        for (int p = 0; p < 2; ++p) {
            const int kc = kc0 + p;
            // x: 2 instr (rows w*16..+7, +8..+15)
            stage16(xs0 + (size_t)kc * 32, bb + p*8192 + (w*16 + 0) * 128);
            stage16(xs1 + (size_t)kc * 32, bb + p*8192 + (w*16 + 8) * 128);
            // B: nt=w hi/lo (src per-lane l*8 halves = l*16 B; dst +lane*16)
            stage16(bhs_ + (size_t)kc * 512 + l * 8,
                    bb + 16384 + p*8192 + w*2048);
            stage16(bls  + (size_t)kc * 512 + l * 8,
                    bb + 16384 + p*8192 + w*2048 + 1024);
        }
    };

    // --- compute-side LDS offsets (wave w's token rows; match swizzle) ---
    const int trow   = w*16 + (l & 15);
    const int t7     = trow & 7;                      // = l&7
    const int xa_off = trow * 128 + ((g       ^ t7) << 4);
    const int xb_off = trow * 128 + (((4 + g) ^ t7) << 4);

    auto COMPUTE = [&](int c) {
        const char* bb = sb + (size_t)(c & 3) * 32768;
#pragma unroll
        for (int p = 0; p < 2; ++p) {
            const float4 xa = *reinterpret_cast<const float4*>(bb + p*8192 + xa_off);
            const float4 xb = *reinterpret_cast<const float4*>(bb + p*8192 + xb_off);
            const char* bp = bb + 16384 + p*8192;
            const f16x8 bh0 = *reinterpret_cast<const f16x8*>(bp + 0*2048 +        (l << 4));
            const f16x8 bl0 = *reinterpret_cast<const f16x8*>(bp + 0*2048 + 1024 + (l << 4));
            const f16x8 bh1 = *reinterpret_cast<const f16x8*>(bp + 1*2048 +        (l << 4));
            const f16x8 bl1 = *reinterpret_cast<const f16x8*>(bp + 1*2048 + 1024 + (l << 4));
            const f16x8 bh2 = *reinterpret_cast<const f16x8*>(bp + 2*2048 +        (l << 4));
            const f16x8 bl2 = *reinterpret_cast<const f16x8*>(bp + 2*2048 + 1024 + (l << 4));
            const f16x8 bh3 = *reinterpret_cast<const f16x8*>(bp + 3*2048 +        (l << 4));
            const f16x8 bl3 = *reinterpret_cast<const f16x8*>(bp + 3*2048 + 1024 + (l << 4));
            f16x8 ah, al_;
            {
                float vs;
                vs = xa.x * LSCALE; ah[0] = (_Float16)vs; al_[0] = (_Float16)(vs - (float)ah[0]);
                vs = xa.y * LSCALE; ah[1] = (_Float16)vs; al_[1] = (_Float16)(vs - (float)ah[1]);
                vs = xa.z * LSCALE; ah[2] = (_Float16)vs; al_[2] = (_Float16)(vs - (float)ah[2]);
                vs = xa.w * LSCALE; ah[3] = (_Float16)vs; al_[3] = (_Float16)(vs - (float)ah[3]);
                vs = xb.x * LSCALE; ah[4] = (_Float16)vs; al_[4] = (_Float16)(vs - (float)ah[4]);
                vs = xb.y * LSCALE; ah[5] = (_Float16)vs; al_[5] = (_Float16)(vs - (float)ah[5]);
                vs = xb.z * LSCALE; ah[6] = (_Float16)vs; al_[6] = (_Float16)(vs - (float)ah[6]);
                vs = xb.w * LSCALE; ah[7] = (_Float16)vs; al_[7] = (_Float16)(vs - (float)ah[7]);
            }
            acc0 = __builtin_amdgcn_mfma_f32_16x16x32_f16(ah,  bh0, acc0, 0, 0, 0);
            acc0 = __builtin_amdgcn_mfma_f32_16x16x32_f16(al_, bh0, acc0, 0, 0, 0);
            acc0 = __builtin_amdgcn_mfma_f32_16x16x32_f16(ah,  bl0, acc0, 0, 0, 0);
            acc1 = __builtin_amdgcn_mfma_f32_16x16x32_f16(ah,  bh1, acc1, 0, 0, 0);
            acc1 = __builtin_amdgcn_mfma_f32_16x16x32_f16(al_, bh1, acc1, 0, 0, 0);
            acc1 = __builtin_amdgcn_mfma_f32_16x16x32_f16(ah,  bl1, acc1, 0, 0, 0);
            acc2 = __builtin_amdgcn_mfma_f32_16x16x32_f16(ah,  bh2, acc2, 0, 0, 0);
            acc2 = __builtin_amdgcn_mfma_f32_16x16x32_f16(al_, bh2, acc2, 0, 0, 0);
            acc2 = __builtin_amdgcn_mfma_f32_16x16x32_f16(ah,  bl2, acc2, 0, 0, 0);
            acc3 = __builtin_amdgcn_mfma_f32_16x16x32_f16(ah,  bh3, acc3, 0, 0, 0);
            acc3 = __builtin_amdgcn_mfma_f32_16x16x32_f16(al_, bh3, acc3, 0, 0, 0);
            acc3 = __builtin_amdgcn_mfma_f32_16x16x32_f16(ah,  bl3, acc3, 0, 0, 0);
        }
    };

    // ---- pipeline: 3 chunks staged ahead, r7-proven pattern ----
    STAGE(0); STAGE(1); STAGE(2);
    for (int c = 0; c < NCH; ++c) {
        if (c <= NCH - 3)      { asm volatile("s_waitcnt vmcnt(16)" ::: "memory"); }
        else if (c == NCH - 2) { asm volatile("s_waitcnt vmcnt(8)"  ::: "memory"); }
        else                   { asm volatile("s_waitcnt vmcnt(0)"  ::: "memory"); }
        __builtin_amdgcn_s_barrier();
        if (c + 3 < NCH) STAGE(c + 3);   // overwrites buf[(c-1)&3]: safe
        __builtin_amdgcn_sched_barrier(0);
        COMPUTE(c);
    }

    // ---- C tiles -> LDS logits (alias buf0; last read chunk 28) ----
    // C layout: col = lane&15, row = (lane>>4)*4 + r; token = w*16 + row.
    {
        float* logits = smem;
        const int col = l & 15;
#pragma unroll
        for (int r = 0; r < 4; ++r) {
            const int t = w*16 + g * 4 + r;
            logits[t * 65 + 0  + col] = acc0[r] * LSCALE2_INV;
            logits[t * 65 + 16 + col] = acc1[r] * LSCALE2_INV;
            logits[t * 65 + 32 + col] = acc2[r] * LSCALE2_INV;
            logits[t * 65 + 48 + col] = acc3[r] * LSCALE2_INV;
        }
    }
    __syncthreads();

    // ---- top-2 + 2-way softmax (frozen scan): thread t handles token t ----
    float* res = smem + TPB * 65;
    if (tid < TPB) {
        const float* lg = smem + tid * 65;
        float m1 = -INFINITY, m2 = -INFINITY;
        int i1 = 0, i2 = 0;
        for (int e = 0; e < E_; ++e) {
            const float v = lg[e] + bias[e];
            if (v > m1)      { m2 = m1; i2 = i1; m1 = v; i1 = e; }
            else if (v > m2) { m2 = v;  i2 = e; }
        }
        const float ex  = expf(m2 - m1);
        const float den = 1.f + ex;
        res[tid*4+0] = 1.f / den;
        res[tid*4+1] = ex / den;
        res[tid*4+2] = (float)i1;
        res[tid*4+3] = (float)i2;
    }
    __syncthreads();

    // ---- output: probs (64 tokens x 64 experts = 4096 floats), float4 ----
    float* ob = out + (size_t)T0 * E_;
#pragma unroll
    for (int i = 0; i < 4; ++i) {
        const int idx = i * 1024 + tid * 4;
        const int t   = idx >> 6;
        const int e0  = idx & 63;
        const float p1 = res[t*4+0];
        const float p2 = res[t*4+1];
        const int   i1 = (int)res[t*4+2];
        const int   i2 = (int)res[t*4+3];
        float4 v;
        v.x = (e0+0 == i1) ? p1 : ((e0+0 == i2) ? p2 : 0.f);
        v.y = (e0+1 == i1) ? p1 : ((e0+1 == i2) ? p2 : 0.f);
        v.z = (e0+2 == i1) ? p1 : ((e0+2 == i2) ? p2 : 0.f);
        v.w = (e0+3 == i1) ? p1 : ((e0+3 == i2) ? p2 : 0.f);
        *reinterpret_cast<float4*>(ob + idx) = v;
    }
    // ids as float values (whole d_out is read as float32)
    if (tid < TPB * 2) {
        out[(size_t)NTOK * E_ + (size_t)T0 * 2 + tid] =
            res[(tid >> 1) * 4 + 2 + (tid & 1)];
    }
}

extern "C" void kernel_launch(void* const* d_in, const int* in_sizes, int n_in,
                              void* d_out, int out_size, void* d_ws, size_t ws_size,
                              hipStream_t stream) {
    const float* x = (const float*)d_in[0];
    const float* W = (const float*)d_in[1];
    const float* b = (const float*)d_in[2];
    float* out     = (float*)d_out;
    _Float16* wh   = (_Float16*)d_ws;                       // 256 KB
    _Float16* wl   = wh + (size_t)4 * NKC * 64 * 8;         // +256 KB

    hipLaunchKernelGGL(prep_w, dim3(64), dim3(256), 0, stream, W, wh, wl);
    hipLaunchKernelGGL(router_mfma, dim3(NTOK / TPB), dim3(256), 0, stream,
                       x, wh, wl, b, out);
}